// Round 5
// baseline (381.507 us; speedup 1.0000x reference)
//
#include <hip/hip_runtime.h>

// ---------------------------------------------------------------------------
// metaLinear: y[t,o] = sum_j x2[t,j] * ( x1[t,:]@W[j*64+o,:] + bvec[j*64+o] )
//   T=16384, IN1=256, IN2=64 (j), OUT=64 (o).
// Round 7: de-lockstep the Wf L2 hotspot.
//   Diagnosis: all 256 blocks sweep the SAME 2MB Wf stream in the SAME order
//   in lockstep -> per-XCD ~64 concurrent requests to the same L2 line ->
//   serialized line service -> effective load latency ~1000+ cyc, exposed
//   every j. Explains why 3 different structures all hit 45.6us and why
//   2x waves bought only 16% (stalls correlated across waves).
//   Fix: (1) per-block j-phase rotation (same-XCD blocks touch 32 different
//   lines at any instant); (2) 4-buffer register ring, prefetch 3 computes
//   ahead (~1200cyc cover); (3) s_setprio(1) around MFMA clusters.
// ---------------------------------------------------------------------------

#define FRAG_SHORTS 512                  // 64 lanes * 8 bf16
#define JSTEP (2 * 16 * FRAG_SHORTS)     // shorts per j (both oh frames)
#define BIAS_OFF ((size_t)(64 * 2 * 16) * FRAG_SHORTS)   // 1048576 shorts

typedef __bf16 bf16x8 __attribute__((ext_vector_type(8)));
typedef float  f32x16 __attribute__((ext_vector_type(16)));

static __device__ __forceinline__ unsigned short f2bf(float f) {
  union { float f; unsigned u; } v; v.f = f;
  unsigned r = v.u + 0x7FFFu + ((v.u >> 16) & 1u);   // RNE
  return (unsigned short)(r >> 16);
}

static __device__ __forceinline__ bf16x8 pack8(float4 a, float4 b) {
  union { bf16x8 v; unsigned short u[8]; } r;
  r.u[0] = f2bf(a.x); r.u[1] = f2bf(a.y); r.u[2] = f2bf(a.z); r.u[3] = f2bf(a.w);
  r.u[4] = f2bf(b.x); r.u[5] = f2bf(b.y); r.u[6] = f2bf(b.z); r.u[7] = f2bf(b.w);
  return r.v;
}

// Pre-shuffle W into A-fragment order (16 frags per (j,oh)):
//   Wf[((j*2+oh)*16 + ks)*512 + lane*8 + e] =
//       bf16( W[row = 64j+32oh+(lane&31)][col = 16ks + 8*(lane>>5) + e] )
// plus 8 bias A-frames at BIAS_OFF, frame f = oh*4+jq (jq = 16-j quarter):
//   Bf[f*512 + lane*8 + e] = bf16( bvec[(jq*16 + 8*(lane>>5)+e)*64 + 32oh + (lane&31)] )
__global__ void prep_w(const float* __restrict__ W, const float* __restrict__ bv,
                       unsigned short* __restrict__ Wf) {
  int idx = blockIdx.x * 256 + threadIdx.x;   // 65536 total
  int r  = idx >> 4;                          // W row 0..4095
  int ks = idx & 15;                          // k-step 0..15
  int j   = r >> 6;
  int o   = r & 63;
  int oh  = o >> 5;
  int l31 = o & 31;
  size_t fb = ((size_t)(j * 2 + oh) * 16 + ks) * FRAG_SHORTS;

  const float4* row = (const float4*)(W + (size_t)r * 256 + ks * 16);
  float4 v0 = row[0], v1 = row[1], v2 = row[2], v3 = row[3];
  ushort4 lo0, lo1, hi0, hi1;
  lo0.x = f2bf(v0.x); lo0.y = f2bf(v0.y); lo0.z = f2bf(v0.z); lo0.w = f2bf(v0.w);
  lo1.x = f2bf(v1.x); lo1.y = f2bf(v1.y); lo1.z = f2bf(v1.z); lo1.w = f2bf(v1.w);
  hi0.x = f2bf(v2.x); hi0.y = f2bf(v2.y); hi0.z = f2bf(v2.z); hi0.w = f2bf(v2.w);
  hi1.x = f2bf(v3.x); hi1.y = f2bf(v3.y); hi1.z = f2bf(v3.z); hi1.w = f2bf(v3.w);
  *(ushort4*)&Wf[fb + l31 * 8 + 0] = lo0;            // lane l31 (lg=0)
  *(ushort4*)&Wf[fb + l31 * 8 + 4] = lo1;
  *(ushort4*)&Wf[fb + 256 + l31 * 8 + 0] = hi0;      // lane 32+l31 (lg=1)
  *(ushort4*)&Wf[fb + 256 + l31 * 8 + 4] = hi1;

  if (idx < 512) {                                   // bias A-frames
    int f   = idx >> 6;                              // 0..7 = oh*4+jq
    int ln  = idx & 63;
    int ohb = f >> 2, jq = f & 3;
    int lb  = ln & 31, lgb = ln >> 5;
    #pragma unroll
    for (int e = 0; e < 8; ++e)
      Wf[BIAS_OFF + (size_t)f * FRAG_SHORTS + ln * 8 + e] =
          f2bf(bv[(jq * 16 + 8 * lgb + e) * 64 + 32 * ohb + lb]);
  }
}

// Main fused kernel. 256 WGs x 512 threads (8 waves = kh(4) x jh(2)).
// Block = (tile-group of 128 tokens, oh). Each wave: 4 token tiles (m=0..3),
// its kh quarter of k-steps (4 frags), its jh half of j (32 j's) -- iterated
// in a per-block ROTATED order so same-XCD blocks never hit the same line.
__global__
__attribute__((amdgpu_flat_work_group_size(512, 512), amdgpu_waves_per_eu(2, 2)))
void meta_main(const float* __restrict__ x1, const float* __restrict__ x2,
               const unsigned short* __restrict__ Wf, float* __restrict__ out) {
  __shared__ __align__(16) unsigned char smem[102400];
  float* sX2 = (float*)smem;                    // 32 KB: x2 transposed [j][t=128]
  float* red = (float*)(smem + 32768);          // 4 slots x 4352 f32 (pad 17)

  const int tid  = threadIdx.x;
  const int lane = tid & 63;
  const int wv   = tid >> 6;
  const int kh   = wv & 3;                      // k-quarter (frags kh*4..+4)
  const int jh   = wv >> 2;                     // j half (32 j's)
  const int l31  = lane & 31;
  const int lg   = lane >> 5;

  const int bid  = blockIdx.x;
  const int oh   = bid & 1;
  const long tile0 = (long)(bid >> 1) * 128;
  const int phase = (bid >> 3) & 31;            // unique per same-XCD block

  // ---- stage x2 -> sX2[j][t] ----
  {
    const float4* s2 = (const float4*)(x2 + tile0 * 64);
    #pragma unroll
    for (int it = 0; it < 4; ++it) {
      int fi4 = it * 512 + tid;
      float4 v = s2[fi4];
      int token = fi4 >> 4;                     // 0..127
      int j0    = (fi4 & 15) * 4;
      sX2[(j0 + 0) * 128 + token] = v.x;
      sX2[(j0 + 1) * 128 + token] = v.y;
      sX2[(j0 + 2) * 128 + token] = v.z;
      sX2[(j0 + 3) * 128 + token] = v.w;
    }
  }

  // ---- x1 B-frags direct global->reg: 4 tiles x 4 ks (this kh quarter) ----
  bf16x8 bf[4][4];
  #pragma unroll
  for (int m = 0; m < 4; ++m) {
    #pragma unroll
    for (int q = 0; q < 4; ++q) {
      const float* p = x1 + (size_t)(tile0 + m * 32 + l31) * 256 +
                       (kh * 4 + q) * 16 + lg * 8;
      bf[m][q] = pack8(*(const float4*)p, *(const float4*)(p + 4));
    }
  }
  __syncthreads();                              // sX2 ready

  f32x16 z;
  #pragma unroll
  for (int r = 0; r < 16; ++r) z[r] = 0.0f;

  // ---- yacc init; kh==0 waves fold the bias term (2 quarters each) ----
  f32x16 y[4];
  #pragma unroll
  for (int m = 0; m < 4; ++m) y[m] = z;
  if (kh == 0) {
    #pragma unroll
    for (int qq = 0; qq < 2; ++qq) {
      int jq = jh * 2 + qq;
      bf16x8 bias = *(const bf16x8*)(Wf + BIAS_OFF +
                                     (size_t)(oh * 4 + jq) * FRAG_SHORTS + lane * 8);
      #pragma unroll
      for (int m = 0; m < 4; ++m) {
        union { bf16x8 v; unsigned short u[8]; } xf;
        #pragma unroll
        for (int e = 0; e < 8; ++e)
          xf.u[e] = f2bf(sX2[(jq * 16 + 8 * lg + e) * 128 + m * 32 + l31]);
        y[m] = __builtin_amdgcn_mfma_f32_32x32x16_bf16(bias, xf.v, y[m], 0, 0, 0);
      }
    }
  }

  // ---- rotated, 4-buffer ring, 3-ahead prefetch, barrier-free j-loop ----
  const unsigned short* wbase0 =
      Wf + ((size_t)(jh * 32 * 2 + oh) * 16 + kh * 4) * FRAG_SHORTS + lane * 8;

#define LOADW(DST, I)                                                           \
  {                                                                             \
    int jj = ((I) + phase) & 31;                                                \
    const unsigned short* p = wbase0 + (size_t)jj * JSTEP;                      \
    DST[0] = *(const bf16x8*)(p + 0 * FRAG_SHORTS);                             \
    DST[1] = *(const bf16x8*)(p + 1 * FRAG_SHORTS);                             \
    DST[2] = *(const bf16x8*)(p + 2 * FRAG_SHORTS);                             \
    DST[3] = *(const bf16x8*)(p + 3 * FRAG_SHORTS);                             \
  }

#define COMPUTE(WREG, I)                                                        \
  {                                                                             \
    const int jg = jh * 32 + (((I) + phase) & 31);                              \
    f32x16 aA, aB;                                                              \
    __builtin_amdgcn_s_setprio(1);                                              \
    aA = __builtin_amdgcn_mfma_f32_32x32x16_bf16(WREG[0], bf[0][0], z, 0, 0, 0);\
    aB = __builtin_amdgcn_mfma_f32_32x32x16_bf16(WREG[0], bf[1][0], z, 0, 0, 0);\
    aA = __builtin_amdgcn_mfma_f32_32x32x16_bf16(WREG[1], bf[0][1], aA, 0, 0, 0);\
    aB = __builtin_amdgcn_mfma_f32_32x32x16_bf16(WREG[1], bf[1][1], aB, 0, 0, 0);\
    aA = __builtin_amdgcn_mfma_f32_32x32x16_bf16(WREG[2], bf[0][2], aA, 0, 0, 0);\
    aB = __builtin_amdgcn_mfma_f32_32x32x16_bf16(WREG[2], bf[1][2], aB, 0, 0, 0);\
    aA = __builtin_amdgcn_mfma_f32_32x32x16_bf16(WREG[3], bf[0][3], aA, 0, 0, 0);\
    aB = __builtin_amdgcn_mfma_f32_32x32x16_bf16(WREG[3], bf[1][3], aB, 0, 0, 0);\
    __builtin_amdgcn_s_setprio(0);                                              \
    float xs0 = sX2[jg * 128 + l31];                                            \
    float xs1 = sX2[jg * 128 + 32 + l31];                                       \
    _Pragma("unroll")                                                           \
    for (int r = 0; r < 16; ++r) {                                              \
      y[0][r] += xs0 * aA[r];                                                   \
      y[1][r] += xs1 * aB[r];                                                   \
    }                                                                           \
    __builtin_amdgcn_s_setprio(1);                                              \
    aA = __builtin_amdgcn_mfma_f32_32x32x16_bf16(WREG[0], bf[2][0], z, 0, 0, 0);\
    aB = __builtin_amdgcn_mfma_f32_32x32x16_bf16(WREG[0], bf[3][0], z, 0, 0, 0);\
    aA = __builtin_amdgcn_mfma_f32_32x32x16_bf16(WREG[1], bf[2][1], aA, 0, 0, 0);\
    aB = __builtin_amdgcn_mfma_f32_32x32x16_bf16(WREG[1], bf[3][1], aB, 0, 0, 0);\
    aA = __builtin_amdgcn_mfma_f32_32x32x16_bf16(WREG[2], bf[2][2], aA, 0, 0, 0);\
    aB = __builtin_amdgcn_mfma_f32_32x32x16_bf16(WREG[2], bf[3][2], aB, 0, 0, 0);\
    aA = __builtin_amdgcn_mfma_f32_32x32x16_bf16(WREG[3], bf[2][3], aA, 0, 0, 0);\
    aB = __builtin_amdgcn_mfma_f32_32x32x16_bf16(WREG[3], bf[3][3], aB, 0, 0, 0);\
    __builtin_amdgcn_s_setprio(0);                                              \
    float xs2 = sX2[jg * 128 + 64 + l31];                                       \
    float xs3 = sX2[jg * 128 + 96 + l31];                                       \
    _Pragma("unroll")                                                           \
    for (int r = 0; r < 16; ++r) {                                              \
      y[2][r] += xs2 * aA[r];                                                   \
      y[3][r] += xs3 * aB[r];                                                   \
    }                                                                           \
  }

  bf16x8 wa[4], wb[4], wc[4], wd[4];
  LOADW(wa, 0); LOADW(wb, 1); LOADW(wc, 2);

  for (int i = 0; i < 32; i += 4) {
    LOADW(wd, i + 3); COMPUTE(wa, i);
    LOADW(wa, i + 4); COMPUTE(wb, i + 1);      // wrap-loads past 31 are
    LOADW(wb, i + 5); COMPUTE(wc, i + 2);      // valid addrs, never computed
    LOADW(wc, i + 6); COMPUTE(wd, i + 3);
  }
#undef COMPUTE
#undef LOADW

  // ---- 8-way partial reduction in 3 LDS phases (pad-17, conflict-free) ----
#define RED_W(S)                                                   \
  { float* b = red + (S) * 4352;                                   \
    _Pragma("unroll") for (int m = 0; m < 4; ++m)                  \
      _Pragma("unroll") for (int r = 0; r < 16; ++r)               \
        b[(m * 64 + lane) * 17 + r] = y[m][r]; }
#define RED_A(S)                                                   \
  { const float* b = red + (S) * 4352;                             \
    _Pragma("unroll") for (int m = 0; m < 4; ++m)                  \
      _Pragma("unroll") for (int r = 0; r < 16; ++r)               \
        y[m][r] += b[(m * 64 + lane) * 17 + r]; }

  if (kh >= 2) RED_W((kh - 2) * 2 + jh);
  __syncthreads();
  if (kh < 2)  RED_A(kh * 2 + jh);
  __syncthreads();
  if (kh == 1) RED_W(jh);
  __syncthreads();
  if (kh == 0) RED_A(jh);
  __syncthreads();
  if (kh == 0 && jh == 1) RED_W(0);
  __syncthreads();
  if (wv == 0) {
    RED_A(0);
    // D layout: col = t = l31, row(o_local) = (r&3) + 8*(r>>2) + 4*lg
    #pragma unroll
    for (int m = 0; m < 4; ++m) {
      float* yo = out + (tile0 + m * 32 + l31) * 64 + oh * 32;
      #pragma unroll
      for (int rq = 0; rq < 4; ++rq) {
        float4 v = make_float4(y[m][4 * rq + 0], y[m][4 * rq + 1],
                               y[m][4 * rq + 2], y[m][4 * rq + 3]);
        *(float4*)(yo + 8 * rq + 4 * lg) = v;
      }
    }
  }
#undef RED_W
#undef RED_A
}

extern "C" void kernel_launch(void* const* d_in, const int* in_sizes, int n_in,
                              void* d_out, int out_size, void* d_ws, size_t ws_size,
                              hipStream_t stream) {
  const float* x1 = (const float*)d_in[0];   // (4,4096,256) f32
  const float* x2 = (const float*)d_in[1];   // (4,4096,64)  f32
  const float* W  = (const float*)d_in[2];   // (4096,256)   f32
  const float* bv = (const float*)d_in[3];   // (4096,)      f32
  float* y = (float*)d_out;                  // (4,4096,64)  f32
  unsigned short* Wf = (unsigned short*)d_ws;  // 2 MB frags + 8 KB bias frames

  prep_w<<<256, 256, 0, stream>>>(W, bv, Wf);
  meta_main<<<256, 512, 0, stream>>>(x1, x2, Wf, y);
}

// Round 6
// 113.352 us; speedup vs baseline: 3.3657x; 3.3657x over previous
//
#include <hip/hip_runtime.h>

// ---------------------------------------------------------------------------
// metaLinear: y[t,o] = sum_j x2[t,j] * ( x1[t,:]@W[j*64+o,:] + bvec[j*64+o] )
//   T=16384, IN1=256, IN2=64 (j), OUT=64 (o).
// Round 8: rotation-only A/B at round-6 register pressure.
//   R7's 4-buffer ring spilled (WRITE 4.6MB->792MB) and destroyed the
//   de-lockstep experiment. This round keeps the EXACT R6 structure
//   (2-buffer register double-buffer, barrier-free j-loop, no setprio) and
//   changes ONE thing: each same-XCD block sweeps j in a rotated order
//   (start phase = per-XCD block slot), so the 32 blocks on an XCD never
//   request the same Wf L2 line/channel at the same instant.
//   Theory: lockstep same-line bursts serialize one L2 channel -> ~1000cyc
//   effective latency per j, correlated across waves (why occupancy/barrier/
//   staging changes were all neutral at 45.6us).
//   Tripwire: WRITE_SIZE must stay ~4.6MB (no spill). Predict dur 45.6->~25us
//   if theory holds; unchanged kills the theory.
// ---------------------------------------------------------------------------

#define FRAG_SHORTS 512                  // 64 lanes * 8 bf16
#define JSTEP (2 * 16 * FRAG_SHORTS)     // shorts per j (both oh frames)
#define BIAS_OFF ((size_t)(64 * 2 * 16) * FRAG_SHORTS)   // 1048576 shorts

typedef __bf16 bf16x8 __attribute__((ext_vector_type(8)));
typedef float  f32x16 __attribute__((ext_vector_type(16)));

static __device__ __forceinline__ unsigned short f2bf(float f) {
  union { float f; unsigned u; } v; v.f = f;
  unsigned r = v.u + 0x7FFFu + ((v.u >> 16) & 1u);   // RNE
  return (unsigned short)(r >> 16);
}

static __device__ __forceinline__ bf16x8 pack8(float4 a, float4 b) {
  union { bf16x8 v; unsigned short u[8]; } r;
  r.u[0] = f2bf(a.x); r.u[1] = f2bf(a.y); r.u[2] = f2bf(a.z); r.u[3] = f2bf(a.w);
  r.u[4] = f2bf(b.x); r.u[5] = f2bf(b.y); r.u[6] = f2bf(b.z); r.u[7] = f2bf(b.w);
  return r.v;
}

// Pre-shuffle W into A-fragment order (16 frags per (j,oh)):
//   Wf[((j*2+oh)*16 + ks)*512 + lane*8 + e] =
//       bf16( W[row = 64j+32oh+(lane&31)][col = 16ks + 8*(lane>>5) + e] )
// plus 8 bias A-frames at BIAS_OFF, frame f = oh*4+jq (jq = 16-j quarter):
//   Bf[f*512 + lane*8 + e] = bf16( bvec[(jq*16 + 8*(lane>>5)+e)*64 + 32oh + (lane&31)] )
__global__ void prep_w(const float* __restrict__ W, const float* __restrict__ bv,
                       unsigned short* __restrict__ Wf) {
  int idx = blockIdx.x * 256 + threadIdx.x;   // 65536 total
  int r  = idx >> 4;                          // W row 0..4095
  int ks = idx & 15;                          // k-step 0..15
  int j   = r >> 6;
  int o   = r & 63;
  int oh  = o >> 5;
  int l31 = o & 31;
  size_t fb = ((size_t)(j * 2 + oh) * 16 + ks) * FRAG_SHORTS;

  const float4* row = (const float4*)(W + (size_t)r * 256 + ks * 16);
  float4 v0 = row[0], v1 = row[1], v2 = row[2], v3 = row[3];
  ushort4 lo0, lo1, hi0, hi1;
  lo0.x = f2bf(v0.x); lo0.y = f2bf(v0.y); lo0.z = f2bf(v0.z); lo0.w = f2bf(v0.w);
  lo1.x = f2bf(v1.x); lo1.y = f2bf(v1.y); lo1.z = f2bf(v1.z); lo1.w = f2bf(v1.w);
  hi0.x = f2bf(v2.x); hi0.y = f2bf(v2.y); hi0.z = f2bf(v2.z); hi0.w = f2bf(v2.w);
  hi1.x = f2bf(v3.x); hi1.y = f2bf(v3.y); hi1.z = f2bf(v3.z); hi1.w = f2bf(v3.w);
  *(ushort4*)&Wf[fb + l31 * 8 + 0] = lo0;            // lane l31 (lg=0)
  *(ushort4*)&Wf[fb + l31 * 8 + 4] = lo1;
  *(ushort4*)&Wf[fb + 256 + l31 * 8 + 0] = hi0;      // lane 32+l31 (lg=1)
  *(ushort4*)&Wf[fb + 256 + l31 * 8 + 4] = hi1;

  if (idx < 512) {                                   // bias A-frames
    int f   = idx >> 6;                              // 0..7 = oh*4+jq
    int ln  = idx & 63;
    int ohb = f >> 2, jq = f & 3;
    int lb  = ln & 31, lgb = ln >> 5;
    #pragma unroll
    for (int e = 0; e < 8; ++e)
      Wf[BIAS_OFF + (size_t)f * FRAG_SHORTS + ln * 8 + e] =
          f2bf(bv[(jq * 16 + 8 * lgb + e) * 64 + 32 * ohb + lb]);
  }
}

// Main fused kernel. 256 WGs x 512 threads (8 waves = kh(4) x jh(2)).
// Block = (tile-group of 128 tokens, oh). Each wave: 4 token tiles (m=0..3),
// its kh quarter of k-steps (4 frags), its jh half of j (32 j's) -- swept in
// a per-block ROTATED order (start = per-XCD slot) to de-lockstep L2.
__global__
__attribute__((amdgpu_flat_work_group_size(512, 512), amdgpu_waves_per_eu(2, 2)))
void meta_main(const float* __restrict__ x1, const float* __restrict__ x2,
               const unsigned short* __restrict__ Wf, float* __restrict__ out) {
  __shared__ __align__(16) unsigned char smem[102400];
  float* sX2 = (float*)smem;                    // 32 KB: x2 transposed [j][t=128]
  float* red = (float*)(smem + 32768);          // 4 slots x 4352 f32 (pad 17)

  const int tid  = threadIdx.x;
  const int lane = tid & 63;
  const int wv   = tid >> 6;
  const int kh   = wv & 3;                      // k-quarter (frags kh*4..+4)
  const int jh   = wv >> 2;                     // j half (32 j's)
  const int l31  = lane & 31;
  const int lg   = lane >> 5;

  const int bid  = blockIdx.x;
  const int oh   = bid & 1;
  const long tile0 = (long)(bid >> 1) * 128;
  const int phase = (bid >> 3) & 31;            // unique per same-XCD block

  // ---- stage x2 -> sX2[j][t] ----
  {
    const float4* s2 = (const float4*)(x2 + tile0 * 64);
    #pragma unroll
    for (int it = 0; it < 4; ++it) {
      int fi4 = it * 512 + tid;
      float4 v = s2[fi4];
      int token = fi4 >> 4;                     // 0..127
      int j0    = (fi4 & 15) * 4;
      sX2[(j0 + 0) * 128 + token] = v.x;
      sX2[(j0 + 1) * 128 + token] = v.y;
      sX2[(j0 + 2) * 128 + token] = v.z;
      sX2[(j0 + 3) * 128 + token] = v.w;
    }
  }

  // ---- x1 B-frags direct global->reg: 4 tiles x 4 ks (this kh quarter) ----
  bf16x8 bf[4][4];
  #pragma unroll
  for (int m = 0; m < 4; ++m) {
    #pragma unroll
    for (int q = 0; q < 4; ++q) {
      const float* p = x1 + (size_t)(tile0 + m * 32 + l31) * 256 +
                       (kh * 4 + q) * 16 + lg * 8;
      bf[m][q] = pack8(*(const float4*)p, *(const float4*)(p + 4));
    }
  }
  __syncthreads();                              // sX2 ready

  f32x16 z;
  #pragma unroll
  for (int r = 0; r < 16; ++r) z[r] = 0.0f;

  // ---- yacc init; kh==0 waves fold the bias term (2 quarters each) ----
  f32x16 y[4];
  #pragma unroll
  for (int m = 0; m < 4; ++m) y[m] = z;
  if (kh == 0) {
    #pragma unroll
    for (int qq = 0; qq < 2; ++qq) {
      int jq = jh * 2 + qq;
      bf16x8 bias = *(const bf16x8*)(Wf + BIAS_OFF +
                                     (size_t)(oh * 4 + jq) * FRAG_SHORTS + lane * 8);
      #pragma unroll
      for (int m = 0; m < 4; ++m) {
        union { bf16x8 v; unsigned short u[8]; } xf;
        #pragma unroll
        for (int e = 0; e < 8; ++e)
          xf.u[e] = f2bf(sX2[(jq * 16 + 8 * lg + e) * 128 + m * 32 + l31]);
        y[m] = __builtin_amdgcn_mfma_f32_32x32x16_bf16(bias, xf.v, y[m], 0, 0, 0);
      }
    }
  }

  // ---- rotated 2-buffer barrier-free j-loop (R6 structure + phase) ----
  const unsigned short* wbase0 =
      Wf + ((size_t)(jh * 32 * 2 + oh) * 16 + kh * 4) * FRAG_SHORTS + lane * 8;

#define LOADW(DST, JJ)                                                          \
  {                                                                             \
    const unsigned short* p = wbase0 + (size_t)(JJ) * JSTEP;                    \
    DST[0] = *(const bf16x8*)(p + 0 * FRAG_SHORTS);                             \
    DST[1] = *(const bf16x8*)(p + 1 * FRAG_SHORTS);                             \
    DST[2] = *(const bf16x8*)(p + 2 * FRAG_SHORTS);                             \
    DST[3] = *(const bf16x8*)(p + 3 * FRAG_SHORTS);                             \
  }

#define COMPUTE(WREG, JJ)                                                       \
  {                                                                             \
    const int jg = jh * 32 + (JJ);                                              \
    f32x16 aA, aB;                                                              \
    aA = __builtin_amdgcn_mfma_f32_32x32x16_bf16(WREG[0], bf[0][0], z, 0, 0, 0);\
    aB = __builtin_amdgcn_mfma_f32_32x32x16_bf16(WREG[0], bf[1][0], z, 0, 0, 0);\
    aA = __builtin_amdgcn_mfma_f32_32x32x16_bf16(WREG[1], bf[0][1], aA, 0, 0, 0);\
    aB = __builtin_amdgcn_mfma_f32_32x32x16_bf16(WREG[1], bf[1][1], aB, 0, 0, 0);\
    aA = __builtin_amdgcn_mfma_f32_32x32x16_bf16(WREG[2], bf[0][2], aA, 0, 0, 0);\
    aB = __builtin_amdgcn_mfma_f32_32x32x16_bf16(WREG[2], bf[1][2], aB, 0, 0, 0);\
    aA = __builtin_amdgcn_mfma_f32_32x32x16_bf16(WREG[3], bf[0][3], aA, 0, 0, 0);\
    aB = __builtin_amdgcn_mfma_f32_32x32x16_bf16(WREG[3], bf[1][3], aB, 0, 0, 0);\
    float xs0 = sX2[jg * 128 + l31];                                            \
    float xs1 = sX2[jg * 128 + 32 + l31];                                       \
    _Pragma("unroll")                                                           \
    for (int r = 0; r < 16; ++r) {                                              \
      y[0][r] += xs0 * aA[r];                                                   \
      y[1][r] += xs1 * aB[r];                                                   \
    }                                                                           \
    aA = __builtin_amdgcn_mfma_f32_32x32x16_bf16(WREG[0], bf[2][0], z, 0, 0, 0);\
    aB = __builtin_amdgcn_mfma_f32_32x32x16_bf16(WREG[0], bf[3][0], z, 0, 0, 0);\
    aA = __builtin_amdgcn_mfma_f32_32x32x16_bf16(WREG[1], bf[2][1], aA, 0, 0, 0);\
    aB = __builtin_amdgcn_mfma_f32_32x32x16_bf16(WREG[1], bf[3][1], aB, 0, 0, 0);\
    aA = __builtin_amdgcn_mfma_f32_32x32x16_bf16(WREG[2], bf[2][2], aA, 0, 0, 0);\
    aB = __builtin_amdgcn_mfma_f32_32x32x16_bf16(WREG[2], bf[3][2], aB, 0, 0, 0);\
    aA = __builtin_amdgcn_mfma_f32_32x32x16_bf16(WREG[3], bf[2][3], aA, 0, 0, 0);\
    aB = __builtin_amdgcn_mfma_f32_32x32x16_bf16(WREG[3], bf[3][3], aB, 0, 0, 0);\
    float xs2 = sX2[jg * 128 + 64 + l31];                                       \
    float xs3 = sX2[jg * 128 + 96 + l31];                                       \
    _Pragma("unroll")                                                           \
    for (int r = 0; r < 16; ++r) {                                              \
      y[2][r] += xs2 * aA[r];                                                   \
      y[3][r] += xs3 * aB[r];                                                   \
    }                                                                           \
  }

  bf16x8 wa[4], wb[4];
  int jc = phase;                               // current j (scalar, SGPR)
  LOADW(wa, jc);
  for (int i = 0; i < 32; i += 2) {
    int jn = jc + 1; if (jn == 32) jn = 0;      // j for wb
    LOADW(wb, jn);
    COMPUTE(wa, jc);
    int jp = jn + 1; if (jp == 32) jp = 0;      // j for next wa (last-iter
    LOADW(wa, jp);                              //  load wraps: valid, unused)
    COMPUTE(wb, jn);
    jc = jp;
  }
#undef COMPUTE
#undef LOADW

  // ---- 8-way partial reduction in 3 LDS phases (pad-17, conflict-free) ----
#define RED_W(S)                                                   \
  { float* b = red + (S) * 4352;                                   \
    _Pragma("unroll") for (int m = 0; m < 4; ++m)                  \
      _Pragma("unroll") for (int r = 0; r < 16; ++r)               \
        b[(m * 64 + lane) * 17 + r] = y[m][r]; }
#define RED_A(S)                                                   \
  { const float* b = red + (S) * 4352;                             \
    _Pragma("unroll") for (int m = 0; m < 4; ++m)                  \
      _Pragma("unroll") for (int r = 0; r < 16; ++r)               \
        y[m][r] += b[(m * 64 + lane) * 17 + r]; }

  if (kh >= 2) RED_W((kh - 2) * 2 + jh);
  __syncthreads();
  if (kh < 2)  RED_A(kh * 2 + jh);
  __syncthreads();
  if (kh == 1) RED_W(jh);
  __syncthreads();
  if (kh == 0) RED_A(jh);
  __syncthreads();
  if (kh == 0 && jh == 1) RED_W(0);
  __syncthreads();
  if (wv == 0) {
    RED_A(0);
    // D layout: col = t = l31, row(o_local) = (r&3) + 8*(r>>2) + 4*lg
    #pragma unroll
    for (int m = 0; m < 4; ++m) {
      float* yo = out + (tile0 + m * 32 + l31) * 64 + oh * 32;
      #pragma unroll
      for (int rq = 0; rq < 4; ++rq) {
        float4 v = make_float4(y[m][4 * rq + 0], y[m][4 * rq + 1],
                               y[m][4 * rq + 2], y[m][4 * rq + 3]);
        *(float4*)(yo + 8 * rq + 4 * lg) = v;
      }
    }
  }
#undef RED_W
#undef RED_A
}

extern "C" void kernel_launch(void* const* d_in, const int* in_sizes, int n_in,
                              void* d_out, int out_size, void* d_ws, size_t ws_size,
                              hipStream_t stream) {
  const float* x1 = (const float*)d_in[0];   // (4,4096,256) f32
  const float* x2 = (const float*)d_in[1];   // (4,4096,64)  f32
  const float* W  = (const float*)d_in[2];   // (4096,256)   f32
  const float* bv = (const float*)d_in[3];   // (4096,)      f32
  float* y = (float*)d_out;                  // (4,4096,64)  f32
  unsigned short* Wf = (unsigned short*)d_ws;  // 2 MB frags + 8 KB bias frames

  prep_w<<<256, 256, 0, stream>>>(W, bv, Wf);
  meta_main<<<256, 512, 0, stream>>>(x1, x2, Wf, y);
}